// Round 12
// baseline (577.628 us; speedup 1.0000x reference)
//
#include <hip/hip_runtime.h>
#include <hip/hip_bf16.h>

#define NN   100000
#define EE   3200000
#define HH   32
#define BB   128
#define KMAX 96
#define LSTRIDE 97       // LDS row stride (97 odd -> conflict-free-ish)
#define NBKT 1024        // fine dst buckets (one per csr block)
#define BSPAN 98         // ceil(NN/NBKT)
#define EBLK 256         // edge-chunk blocks
#define CHUNK 12500      // EE / EBLK exactly

typedef float f32x4 __attribute__((ext_vector_type(4)));

// ws layout (bytes), non-overlapping (~47.7 MB)
static constexpr size_t Q_OFF      = 0;           // N*64B bf16 rows = 6.4 MB
static constexpr size_t EPACK_OFF  = 6400000;     // EE int = 12.8 MB
static constexpr size_t H_OFF      = 19200000;    // N*32 f32 = 12.8 MB
static constexpr size_t SRC_OFF    = 32000000;    // EE int dense csr
static constexpr size_t OFF_OFF    = 44800000;    // (N+1) int
static constexpr size_t HIST_OFF   = 45300000;    // EBLK*NBKT int = 1 MB
static constexpr size_t CUR_OFF    = 46400000;    // NBKT int cursors
static constexpr size_t BBASE_OFF  = 47500000;    // (NBKT+1) int
static constexpr size_t STATS_OFF  = 47600000;    // 4 layers x 64 f32 = 1024 B
static constexpr size_t POOLED_OFF = 47601024;    // B*32 f32 = 16384 B
static constexpr size_t PCNT_OFF   = 47617408;    // B f32 = 512 B
static constexpr size_t TOTAL_OFF  = 47617920;    // NBKT int totals = 4096 B
static constexpr size_t ZERO_OFF   = STATS_OFF;
static constexpr size_t ZERO_BYTES = 22016;       // stats+pooled+pcnt+total contiguous

// ---- K1: per-block LDS histogram of dst buckets; also accumulate global totals
__global__ __launch_bounds__(256) void hist_kernel(const int* __restrict__ ei,
                                                   int* __restrict__ hist,
                                                   int* __restrict__ total) {
    __shared__ int lh[NBKT];
    int tid = threadIdx.x, blk = blockIdx.x;
    for (int i = tid; i < NBKT; i += 256) lh[i] = 0;
    __syncthreads();
    int e0 = blk * CHUNK;
    for (int e = e0 + tid; e < e0 + CHUNK; e += 256) {
        int d = ei[EE + e];
        atomicAdd(&lh[d / BSPAN], 1);
    }
    __syncthreads();
    for (int i = tid; i < NBKT; i += 256) {
        int c = lh[i];
        hist[blk * NBKT + i] = c;
        if (c > 0) atomicAdd(&total[i], c);
    }
}

// ---- K2: scan 1024 totals -> bbase, cursor (no serial 256-deep load chain)
__global__ __launch_bounds__(1024) void bucket_scan_kernel(const int* __restrict__ total,
                                                           int* __restrict__ bbase,
                                                           int* __restrict__ cursor) {
    __shared__ int sm[NBKT];
    int t = threadIdx.x;
    int mine = total[t];
    sm[t] = mine;
    __syncthreads();
    for (int off = 1; off < NBKT; off <<= 1) {
        int v = (t >= off) ? sm[t - off] : 0;
        __syncthreads();
        sm[t] += v;
        __syncthreads();
    }
    int base = sm[t] - mine;   // exclusive
    bbase[t] = base;
    cursor[t] = base;
    if (t == NBKT - 1) bbase[NBKT] = sm[t];
}

// ---- K3: scatter packed (src | dstoff<<17); block allocates bucket space via
// one global atomicAdd per (block,bucket) using the hist counts.
__global__ __launch_bounds__(256) void scatter_kernel(const int* __restrict__ ei,
                                                      const int* __restrict__ hist,
                                                      int* __restrict__ cursor,
                                                      int* __restrict__ epack) {
    __shared__ int lbs[NBKT];
    __shared__ int lh[NBKT];
    int tid = threadIdx.x, blk = blockIdx.x;
    for (int i = tid; i < NBKT; i += 256) {
        int c = hist[blk * NBKT + i];
        lbs[i] = (c > 0) ? atomicAdd(&cursor[i], c) : 0;
        lh[i] = 0;
    }
    __syncthreads();
    int e0 = blk * CHUNK;
    for (int e = e0 + tid; e < e0 + CHUNK; e += 256) {
        int s = ei[e];
        int d = ei[EE + e];
        int b = d / BSPAN;
        int slot = lbs[b] + atomicAdd(&lh[b], 1);
        epack[slot] = s | ((d - b * BSPAN) << 17);
    }
}

// ---- K4: compact CSR build — one bucket per block, single scan of its epack slice
__global__ __launch_bounds__(256) void csr_compact_kernel(const int* __restrict__ epack,
                                                          const int* __restrict__ bbase,
                                                          int* __restrict__ off,
                                                          int* __restrict__ srcs) {
    __shared__ int lcnt[BSPAN];
    __shared__ int lbase[BSPAN + 1];
    __shared__ int lcsr[BSPAN * LSTRIDE];   // 98*97*4 = 38024 B
    int b = blockIdx.x;
    int base = b * BSPAN;
    int span = NN - base;
    if (span <= 0) return;
    if (span > BSPAN) span = BSPAN;
    int tid = threadIdx.x;
    for (int i = tid; i < span; i += 256) lcnt[i] = 0;
    __syncthreads();
    int p0 = bbase[b], p1 = bbase[b + 1];
    for (int i = p0 + tid; i < p1; i += 256) {
        int wd = epack[i];
        int ld = wd >> 17;
        int slot = atomicAdd(&lcnt[ld], 1);
        if (slot < KMAX) lcsr[ld * LSTRIDE + slot] = wd & 0x1FFFF;
    }
    __syncthreads();
    if (tid == 0) {
        int run = 0;
        for (int i = 0; i < span; i++) { lbase[i] = run; run += min(lcnt[i], KMAX); }
        lbase[span] = run;
    }
    __syncthreads();
    for (int i = tid; i < span; i += 256) off[base + i] = p0 + lbase[i];
    if (base + span == NN && tid == 0) off[NN] = p0 + lbase[span];
    int m = lbase[span];
    for (int j = tid; j < m; j += 256) {
        int lo = 0, hi = span - 1;
        while (lo < hi) {
            int mid = (lo + hi + 1) >> 1;
            if (lbase[mid] <= j) lo = mid; else hi = mid - 1;
        }
        srcs[p0 + j] = lcsr[lo * LSTRIDE + (j - lbase[lo])];
    }
}

__device__ __forceinline__ unsigned bf16rn(float f) {
    unsigned b = __float_as_uint(f);
    return (b + 0x7fffu + ((b >> 16) & 1u)) >> 16;   // RNE
}

__device__ __forceinline__ void acc_row(float* a, uint4 v) {
    a[0] += __uint_as_float(v.x << 16);
    a[1] += __uint_as_float(v.x & 0xffff0000u);
    a[2] += __uint_as_float(v.y << 16);
    a[3] += __uint_as_float(v.y & 0xffff0000u);
    a[4] += __uint_as_float(v.z << 16);
    a[5] += __uint_as_float(v.z & 0xffff0000u);
    a[6] += __uint_as_float(v.w << 16);
    a[7] += __uint_as_float(v.w & 0xffff0000u);
}

// ---- projection (layer 0 only, FIN=128): q(bf16) = x @ w1, 4-way K-split.
template <int FIN>
__global__ __launch_bounds__(256) void proj_kernel(const float* __restrict__ hin,
                                                   const float* __restrict__ w1,
                                                   const float* __restrict__ stats_prev,
                                                   const float* __restrict__ gamma,
                                                   const float* __restrict__ beta,
                                                   uint4* __restrict__ q4) {
    constexpr int JC = FIN / 4;           // K rows per wave
    __shared__ float sa[32], sc[32];
    __shared__ float part[4 * 64 * 33];   // [wv][node][ch], +1 pad -> 33792 B
    int tid = threadIdx.x;
    if constexpr (FIN == 32) {
        if (tid < 32) {
            float mean = stats_prev[tid] * (1.0f / NN);
            float var  = fmaxf(stats_prev[32 + tid] * (1.0f / NN) - mean * mean, 0.f);
            float av = gamma[tid] * rsqrtf(var + 1e-5f);
            sa[tid] = av;
            sc[tid] = beta[tid] - mean * av;
        }
        __syncthreads();
    }
    int wv = __builtin_amdgcn_readfirstlane(tid >> 6);   // K-part, wave-uniform
    int ln = tid & 63;                                   // node within block
    int n = blockIdx.x * 64 + ln;
    float acc[32];
#pragma unroll
    for (int c = 0; c < 32; c++) acc[c] = 0.f;
    if (n < NN) {
        const float4* h4 = (const float4*)(hin + (size_t)n * FIN + wv * JC);
        float hv[JC];
#pragma unroll
        for (int k = 0; k < JC / 4; k++) {
            float4 v = h4[k];
            hv[4*k] = v.x; hv[4*k+1] = v.y; hv[4*k+2] = v.z; hv[4*k+3] = v.w;
        }
        if constexpr (FIN == 32) {
#pragma unroll
            for (int j = 0; j < JC; j++) hv[j] = fmaf(hv[j], sa[wv * JC + j], sc[wv * JC + j]);
        }
#pragma unroll 4
        for (int j = 0; j < JC; j++) {
            float hvj = hv[j];
            const float* wrow = w1 + (size_t)(wv * JC + j) * 32;  // wave-uniform -> s_load
#pragma unroll
            for (int c = 0; c < 32; c++) acc[c] = fmaf(hvj, wrow[c], acc[c]);
        }
    }
    float* my = part + (wv * 64 + ln) * 33;
#pragma unroll
    for (int c = 0; c < 32; c++) my[c] = acc[c];
    __syncthreads();
    int node = tid >> 2, p = tid & 3;
    int n2 = blockIdx.x * 64 + node;
    if (n2 >= NN) return;
    float r[8];
#pragma unroll
    for (int k = 0; k < 8; k++) {
        int c = p * 8 + k;
        r[k] = (part[(0 * 64 + node) * 33 + c] + part[(1 * 64 + node) * 33 + c])
             + (part[(2 * 64 + node) * 33 + c] + part[(3 * 64 + node) * 33 + c]);
    }
    uint4 u;
    u.x = bf16rn(r[0]) | (bf16rn(r[1]) << 16);
    u.y = bf16rn(r[2]) | (bf16rn(r[3]) << 16);
    u.z = bf16rn(r[4]) | (bf16rn(r[5]) << 16);
    u.w = bf16rn(r[6]) | (bf16rn(r[7]) << 16);
    q4[(size_t)n2 * 4 + p] = u;
}

// ---- projection (layers 1..3, FIN=32): one node per thread. q = BN(h) @ w1.
// hv[32]+o[8] live, all compile-time indices (no spill); w1 in LDS, inner reads
// are wave-uniform broadcasts. One barrier (staging), 391 blocks x 256.
__global__ __launch_bounds__(256) void proj32_kernel(const float* __restrict__ hin,
                                                     const float* __restrict__ w1,
                                                     const float* __restrict__ stats_prev,
                                                     const float* __restrict__ gamma,
                                                     const float* __restrict__ beta,
                                                     uint4* __restrict__ q4) {
    __shared__ float w1t[32 * 33];
    __shared__ float sa[32], sc[32];
    int tid = threadIdx.x;
    for (int i = tid; i < 1024; i += 256) w1t[(i >> 5) * 33 + (i & 31)] = w1[i];
    if (tid < 32) {
        float mean = stats_prev[tid] * (1.0f / NN);
        float var  = fmaxf(stats_prev[32 + tid] * (1.0f / NN) - mean * mean, 0.f);
        float av = gamma[tid] * rsqrtf(var + 1e-5f);
        sa[tid] = av;
        sc[tid] = beta[tid] - mean * av;
    }
    __syncthreads();
    int n = blockIdx.x * 256 + tid;
    if (n >= NN) return;
    float hv[32];
    const float4* h4 = (const float4*)(hin + (size_t)n * 32);
#pragma unroll
    for (int k = 0; k < 8; k++) {
        float4 v = h4[k];
        hv[4*k] = v.x; hv[4*k+1] = v.y; hv[4*k+2] = v.z; hv[4*k+3] = v.w;
    }
#pragma unroll
    for (int j = 0; j < 32; j++) hv[j] = fmaf(hv[j], sa[j], sc[j]);
#pragma unroll
    for (int cc = 0; cc < 4; cc++) {
        float o[8];
#pragma unroll
        for (int k = 0; k < 8; k++) o[k] = 0.f;
#pragma unroll
        for (int j = 0; j < 32; j++) {
            float hj = hv[j];
            const float* wr = w1t + j * 33 + cc * 8;
#pragma unroll
            for (int k = 0; k < 8; k++) o[k] = fmaf(hj, wr[k], o[k]);
        }
        uint4 u;
        u.x = bf16rn(o[0]) | (bf16rn(o[1]) << 16);
        u.y = bf16rn(o[2]) | (bf16rn(o[3]) << 16);
        u.z = bf16rn(o[4]) | (bf16rn(o[5]) << 16);
        u.w = bf16rn(o[6]) | (bf16rn(o[7]) << 16);
        q4[(size_t)n * 4 + cc] = u;
    }
}

// ---- fused gather + MLP (r7-verified, DO NOT TOUCH): 4 lanes/node, lane p owns
// channels p*8..p*8+7 (16B slice -> 4-lane coalesced 64B rows), 8-unrolled.
// Epilogue: u -> LDS tile, 32x32 matmul from LDS w2, relu, store h, BN stats.
__global__ __launch_bounds__(256) void gather_mlp_kernel(const uint4* __restrict__ q4,
                                                         const int* __restrict__ srcs,
                                                         const int* __restrict__ off,
                                                         const float* __restrict__ b1,
                                                         const float* __restrict__ w2,
                                                         const float* __restrict__ b2,
                                                         float* __restrict__ hout,
                                                         float* __restrict__ stats) {
    __shared__ float w2t[32 * 33];
    __shared__ float ut[64 * 33];     // 64 nodes x 32 ch (+pad)
    __shared__ float pst[16 * 16];    // 4 waves x 4 p-lanes x (8 s + 8 sq)
    int tid = threadIdx.x;
    for (int i = tid; i < 1024; i += 256) w2t[(i >> 5) * 33 + (i & 31)] = w2[i];
    int t = blockIdx.x * 256 + tid;
    int n = t >> 2;                   // 4 lanes/node, 64 nodes/block
    int p = tid & 3;
    int node64 = tid >> 2;
    bool valid = (n < NN);
    float a[8];
#pragma unroll
    for (int k = 0; k < 8; k++) a[k] = valid ? b1[p * 8 + k] : 0.f;
    if (valid) {
        acc_row(a, q4[(size_t)n * 4 + p]);   // self term
        int o0 = off[n];
        int d = off[n + 1] - o0;
        const int* lst = srcs + o0;
        int i = 0;
        for (; i + 8 <= d; i += 8) {
            int s0 = __builtin_nontemporal_load(lst + i);
            int s1 = __builtin_nontemporal_load(lst + i + 1);
            int s2 = __builtin_nontemporal_load(lst + i + 2);
            int s3 = __builtin_nontemporal_load(lst + i + 3);
            int s4 = __builtin_nontemporal_load(lst + i + 4);
            int s5 = __builtin_nontemporal_load(lst + i + 5);
            int s6 = __builtin_nontemporal_load(lst + i + 6);
            int s7 = __builtin_nontemporal_load(lst + i + 7);
            uint4 v0 = q4[(size_t)s0 * 4 + p];
            uint4 v1 = q4[(size_t)s1 * 4 + p];
            uint4 v2 = q4[(size_t)s2 * 4 + p];
            uint4 v3 = q4[(size_t)s3 * 4 + p];
            uint4 v4 = q4[(size_t)s4 * 4 + p];
            uint4 v5 = q4[(size_t)s5 * 4 + p];
            uint4 v6 = q4[(size_t)s6 * 4 + p];
            uint4 v7 = q4[(size_t)s7 * 4 + p];
            acc_row(a, v0); acc_row(a, v1); acc_row(a, v2); acc_row(a, v3);
            acc_row(a, v4); acc_row(a, v5); acc_row(a, v6); acc_row(a, v7);
        }
        for (; i < d; i++) {
            int s = __builtin_nontemporal_load(lst + i);
            acc_row(a, q4[(size_t)s * 4 + p]);
        }
    }
    // u = relu(z) -> LDS tile
    float* urow = ut + node64 * 33 + p * 8;
#pragma unroll
    for (int k = 0; k < 8; k++) urow[k] = fmaxf(a[k], 0.f);
    __syncthreads();
    // 32x32 matmul: this lane computes channels p*8..p*8+7 of node node64
    int base = p * 8;
    float o[8];
#pragma unroll
    for (int k = 0; k < 8; k++) o[k] = valid ? b2[base + k] : 0.f;
    const float* un = ut + node64 * 33;
#pragma unroll 8
    for (int j = 0; j < 32; j++) {
        float uj = un[j];
        const float* wr = w2t + j * 33 + base;
#pragma unroll
        for (int k = 0; k < 8; k++) o[k] = fmaf(uj, wr[k], o[k]);
    }
#pragma unroll
    for (int k = 0; k < 8; k++) o[k] = fmaxf(o[k], 0.f);
    if (valid) {
        f32x4 h0, h1;
        h0.x = o[0]; h0.y = o[1]; h0.z = o[2]; h0.w = o[3];
        h1.x = o[4]; h1.y = o[5]; h1.z = o[6]; h1.w = o[7];
        f32x4* hr = (f32x4*)(hout + (size_t)n * 32 + base);
        __builtin_nontemporal_store(h0, hr);
        __builtin_nontemporal_store(h1, hr + 1);
    } else {
#pragma unroll
        for (int k = 0; k < 8; k++) o[k] = 0.f;
    }
    // BN stats: reduce across the wave's 16 nodes (same-p lanes stride 4)
    float s[8], q[8];
#pragma unroll
    for (int k = 0; k < 8; k++) { s[k] = o[k]; q[k] = o[k] * o[k]; }
#pragma unroll
    for (int m = 4; m < 64; m <<= 1) {
#pragma unroll
        for (int k = 0; k < 8; k++) {
            s[k] += __shfl_xor(s[k], m);
            q[k] += __shfl_xor(q[k], m);
        }
    }
    int wv = tid >> 6;
    if ((tid & 63) < 4) {
        float* ps = pst + (wv * 4 + p) * 16;
#pragma unroll
        for (int k = 0; k < 8; k++) { ps[k] = s[k]; ps[8 + k] = q[k]; }
    }
    __syncthreads();
    if (tid < 64) {
        int c = tid & 31;
        int issq = tid >> 5;
        int psel = c >> 3, k = c & 7;
        float acc = 0.f;
#pragma unroll
        for (int w = 0; w < 4; w++) acc += pst[(w * 4 + psel) * 16 + issq * 8 + k];
        atomicAdd(&stats[issq * 32 + c], acc);
    }
}

// ---- pooling: segment sums of raw h3 (sorted batch -> run-length flush)
#define PR 16
__global__ __launch_bounds__(256) void pool_kernel(const float* __restrict__ h,
                                                   const int* __restrict__ batch,
                                                   float* __restrict__ pooled,
                                                   float* __restrict__ pcnt) {
    int t = blockIdx.x * 256 + threadIdx.x;
    int c = t & 31;
    int g = t >> 5;
    int r0 = g * PR;
    if (r0 >= NN) return;
    int r1 = min(r0 + PR, NN);
    int cur = batch[r0];
    float acc = 0.f, cn = 0.f;
    for (int rr = r0; rr < r1; rr++) {
        int b = batch[rr];
        if (b != cur) {
            atomicAdd(&pooled[cur * 32 + c], acc);
            if (c == 0) atomicAdd(&pcnt[cur], cn);
            acc = 0.f; cn = 0.f; cur = b;
        }
        acc += h[(size_t)rr * 32 + c];
        cn += 1.f;
    }
    atomicAdd(&pooled[cur * 32 + c], acc);
    if (c == 0) atomicAdd(&pcnt[cur], cn);
}

// ---- head: BN3 (from raw stats3) on pooled means, fc1+relu, fc2, log_softmax
__global__ __launch_bounds__(128) void head_kernel(const float* __restrict__ pooled,
                                                   const float* __restrict__ pcnt,
                                                   const float* __restrict__ stats3,
                                                   const float* __restrict__ g3,
                                                   const float* __restrict__ be3,
                                                   const float* __restrict__ fc1w,
                                                   const float* __restrict__ fc1b,
                                                   const float* __restrict__ fc2w,
                                                   const float* __restrict__ fc2b,
                                                   float* __restrict__ out) {
    __shared__ float sa[32], sc[32];
    int g = threadIdx.x;
    if (g < 32) {
        float mean = stats3[g] * (1.0f / NN);
        float var  = fmaxf(stats3[32 + g] * (1.0f / NN) - mean * mean, 0.f);
        float av = g3[g] * rsqrtf(var + 1e-5f);
        sa[g] = av;
        sc[g] = be3[g] - mean * av;
    }
    __syncthreads();
    if (g >= BB) return;
    float inv = 1.f / fmaxf(pcnt[g], 1.f);
    float xv[32];
#pragma unroll
    for (int c = 0; c < 32; c++) xv[c] = fmaf(sa[c], pooled[g * 32 + c] * inv, sc[c]);
    float u[32];
#pragma unroll 4
    for (int k = 0; k < 32; k++) {
        float s = fc1b[k];
#pragma unroll
        for (int c = 0; c < 32; c++) s = fmaf(xv[c], fc1w[c * 32 + k], s);
        u[k] = fmaxf(s, 0.f);
    }
    float l[8];
#pragma unroll
    for (int o = 0; o < 8; o++) {
        float s = fc2b[o];
#pragma unroll
        for (int k = 0; k < 32; k++) s = fmaf(u[k], fc2w[k * 8 + o], s);
        l[o] = s;
    }
    float m = l[0];
#pragma unroll
    for (int o = 1; o < 8; o++) m = fmaxf(m, l[o]);
    float se = 0.f;
#pragma unroll
    for (int o = 0; o < 8; o++) se += expf(l[o] - m);
    float lse = logf(se) + m;
#pragma unroll
    for (int o = 0; o < 8; o++) out[g * 8 + o] = l[o] - lse;
}

extern "C" void kernel_launch(void* const* d_in, const int* in_sizes, int n_in,
                              void* d_out, int out_size, void* d_ws, size_t ws_size,
                              hipStream_t stream) {
    const float* x    = (const float*)d_in[0];
    const int*   ei   = (const int*)d_in[1];
    const int*   batch= (const int*)d_in[2];
    const float* w1_0 = (const float*)d_in[3];
    const float* b1_0 = (const float*)d_in[4];
    const float* w2_0 = (const float*)d_in[5];
    const float* b2_0 = (const float*)d_in[6];
    const float* g_0  = (const float*)d_in[7];
    const float* be_0 = (const float*)d_in[8];
    const float* w1s  = (const float*)d_in[9];
    const float* b1s  = (const float*)d_in[10];
    const float* w2s  = (const float*)d_in[11];
    const float* b2s  = (const float*)d_in[12];
    const float* gs   = (const float*)d_in[13];
    const float* bes  = (const float*)d_in[14];
    const float* fc1w = (const float*)d_in[15];
    const float* fc1b = (const float*)d_in[16];
    const float* fc2w = (const float*)d_in[17];
    const float* fc2b = (const float*)d_in[18];
    float* out = (float*)d_out;

    char* ws = (char*)d_ws;
    uint4*    q4     = (uint4*)(ws + Q_OFF);        // [N][4] uint4 (64B rows)
    int*      epack  = (int*)(ws + EPACK_OFF);
    float*    h      = (float*)(ws + H_OFF);
    int*      srcs   = (int*)(ws + SRC_OFF);
    int*      off    = (int*)(ws + OFF_OFF);
    int*      hist   = (int*)(ws + HIST_OFF);
    int*      cursor = (int*)(ws + CUR_OFF);
    int*      bbase  = (int*)(ws + BBASE_OFF);
    float*    stats  = (float*)(ws + STATS_OFF);   // 4 slots x 64
    float*    pooled = (float*)(ws + POOLED_OFF);
    float*    pcnt   = (float*)(ws + PCNT_OFF);
    int*      total  = (int*)(ws + TOTAL_OFF);

    (void)hipMemsetAsync(ws + ZERO_OFF, 0, ZERO_BYTES, stream);

    // CSR build chain
    hist_kernel<<<EBLK, 256, 0, stream>>>(ei, hist, total);
    bucket_scan_kernel<<<1, NBKT, 0, stream>>>(total, bbase, cursor);
    scatter_kernel<<<EBLK, 256, 0, stream>>>(ei, hist, cursor, epack);
    csr_compact_kernel<<<NBKT, 256, 0, stream>>>(epack, bbase, off, srcs);

    const int pblk = (NN + 63) / 64;
    const int p32blk = (NN + 255) / 256;     // 391
    const int gblk = (NN * 4 + 255) / 256;   // 1563

    // layer 0 (F_IN=128, no input BN)
    proj_kernel<128><<<pblk, 256, 0, stream>>>(x, w1_0, nullptr, nullptr, nullptr, q4);
    gather_mlp_kernel<<<gblk, 256, 0, stream>>>(q4, srcs, off, b1_0, w2_0, b2_0, h, stats);

    // layers 1..3, prev BN computed in proj32 from raw stats slot
    for (int i = 0; i < 3; i++) {
        const float* st_prev = stats + i * 64;
        proj32_kernel<<<p32blk, 256, 0, stream>>>(h, w1s + i * 1024, st_prev,
                                                  gs + i * 32, bes + i * 32, q4);
        gather_mlp_kernel<<<gblk, 256, 0, stream>>>(q4, srcs, off, b1s + i * 32,
                                                    w2s + i * 1024, b2s + i * 32, h,
                                                    stats + (i + 1) * 64);
    }

    int pthreads = ((NN + PR - 1) / PR) * 32;
    pool_kernel<<<(pthreads + 255) / 256, 256, 0, stream>>>(h, batch, pooled, pcnt);
    head_kernel<<<1, 128, 0, stream>>>(pooled, pcnt, stats + 3 * 64, gs + 2 * 32,
                                       bes + 2 * 32, fc1w, fc1b, fc2w, fc2b, out);
}

// Round 13
// 539.745 us; speedup vs baseline: 1.0702x; 1.0702x over previous
//
#include <hip/hip_runtime.h>
#include <hip/hip_bf16.h>

#define NN   100000
#define EE   3200000
#define HH   32
#define BB   128
#define KMAX 96
#define LSTRIDE 97       // LDS row stride (97 odd -> conflict-free-ish)
#define NBKT 1024        // fine dst buckets (one per csr block)
#define BSPAN 98         // ceil(NN/NBKT)
#define EBLK 256         // edge-chunk blocks
#define CHUNK 12500      // EE / EBLK exactly
#define SBT  512         // scatter block threads

typedef float f32x4 __attribute__((ext_vector_type(4)));

// ws layout (bytes), non-overlapping (~47.7 MB)
static constexpr size_t Q_OFF      = 0;           // N*64B bf16 rows = 6.4 MB
static constexpr size_t EPACK_OFF  = 6400000;     // EE int = 12.8 MB
static constexpr size_t H_OFF      = 19200000;    // N*32 f32 = 12.8 MB
static constexpr size_t SRC_OFF    = 32000000;    // EE int dense csr
static constexpr size_t OFF_OFF    = 44800000;    // (N+1) int
static constexpr size_t HIST_OFF   = 45300000;    // EBLK*NBKT int = 1 MB
static constexpr size_t CUR_OFF    = 46400000;    // NBKT int cursors
static constexpr size_t BBASE_OFF  = 47500000;    // (NBKT+1) int
static constexpr size_t STATS_OFF  = 47600000;    // 4 layers x 64 f32 = 1024 B
static constexpr size_t POOLED_OFF = 47601024;    // B*32 f32 = 16384 B
static constexpr size_t PCNT_OFF   = 47617408;    // B f32 = 512 B
static constexpr size_t TOTAL_OFF  = 47617920;    // NBKT int totals = 4096 B
static constexpr size_t ZERO_OFF   = STATS_OFF;
static constexpr size_t ZERO_BYTES = 22016;       // stats+pooled+pcnt+total contiguous

// ---- K1: per-block LDS histogram of dst buckets; also accumulate global totals
__global__ __launch_bounds__(256) void hist_kernel(const int* __restrict__ ei,
                                                   int* __restrict__ hist,
                                                   int* __restrict__ total) {
    __shared__ int lh[NBKT];
    int tid = threadIdx.x, blk = blockIdx.x;
    for (int i = tid; i < NBKT; i += 256) lh[i] = 0;
    __syncthreads();
    int e0 = blk * CHUNK;
    for (int e = e0 + tid; e < e0 + CHUNK; e += 256) {
        int d = ei[EE + e];
        atomicAdd(&lh[d / BSPAN], 1);
    }
    __syncthreads();
    for (int i = tid; i < NBKT; i += 256) {
        int c = lh[i];
        hist[blk * NBKT + i] = c;
        if (c > 0) atomicAdd(&total[i], c);
    }
}

// ---- K2: scan 1024 totals -> bbase, cursor (no serial 256-deep load chain)
__global__ __launch_bounds__(1024) void bucket_scan_kernel(const int* __restrict__ total,
                                                           int* __restrict__ bbase,
                                                           int* __restrict__ cursor) {
    __shared__ int sm[NBKT];
    int t = threadIdx.x;
    int mine = total[t];
    sm[t] = mine;
    __syncthreads();
    for (int off = 1; off < NBKT; off <<= 1) {
        int v = (t >= off) ? sm[t - off] : 0;
        __syncthreads();
        sm[t] += v;
        __syncthreads();
    }
    int base = sm[t] - mine;   // exclusive
    bbase[t] = base;
    cursor[t] = base;
    if (t == NBKT - 1) bbase[NBKT] = sm[t];
}

// ---- K3: LDS-staged scatter. Bin the chunk's packed edges into an LDS staging
// buffer at bucket-local offsets (from the precomputed hist row), then burst-
// write each bucket run contiguously -> every epack line fully dirtied in one
// window (kills the 6x write amplification of per-edge scattered dwords).
__global__ __launch_bounds__(SBT) void scatter_kernel(const int* __restrict__ ei,
                                                      const int* __restrict__ hist,
                                                      int* __restrict__ cursor,
                                                      int* __restrict__ epack) {
    __shared__ int st[CHUNK];         // 50000 B staging
    __shared__ int lbs[NBKT];         // global base per bucket
    __shared__ int lbase[NBKT + 1];   // local exclusive offsets
    __shared__ int lrun[NBKT];        // running counters
    __shared__ int psum[SBT];
    int tid = threadIdx.x, blk = blockIdx.x;
    int b0 = 2 * tid, b1 = 2 * tid + 1;
    int c0 = hist[blk * NBKT + b0];
    int c1 = hist[blk * NBKT + b1];
    psum[tid] = c0 + c1;
    __syncthreads();
    for (int off = 1; off < SBT; off <<= 1) {
        int v = (tid >= off) ? psum[tid - off] : 0;
        __syncthreads();
        psum[tid] += v;
        __syncthreads();
    }
    int base = psum[tid] - (c0 + c1);   // exclusive over bucket pairs
    lbase[b0] = base;
    lbase[b1] = base + c0;
    if (tid == SBT - 1) lbase[NBKT] = psum[tid];
    lrun[b0] = 0; lrun[b1] = 0;
    lbs[b0] = c0 ? atomicAdd(&cursor[b0], c0) : 0;
    lbs[b1] = c1 ? atomicAdd(&cursor[b1], c1) : 0;
    __syncthreads();
    // bin into staging
    int e0 = blk * CHUNK;
    for (int e = e0 + tid; e < e0 + CHUNK; e += SBT) {
        int s = ei[e];
        int d = ei[EE + e];
        int b = d / BSPAN;
        int slot = lbase[b] + atomicAdd(&lrun[b], 1);
        st[slot] = s | ((d - b * BSPAN) << 17);
    }
    __syncthreads();
    // burst out: consecutive j -> consecutive addresses within bucket runs
    for (int j = tid; j < CHUNK; j += SBT) {
        int lo = 0, hi = NBKT - 1;
        while (lo < hi) {
            int mid = (lo + hi + 1) >> 1;
            if (lbase[mid] <= j) lo = mid; else hi = mid - 1;
        }
        epack[lbs[lo] + (j - lbase[lo])] = st[j];
    }
}

// ---- K4: compact CSR build — one bucket per block, single scan of its epack slice
__global__ __launch_bounds__(256) void csr_compact_kernel(const int* __restrict__ epack,
                                                          const int* __restrict__ bbase,
                                                          int* __restrict__ off,
                                                          int* __restrict__ srcs) {
    __shared__ int lcnt[BSPAN];
    __shared__ int lbase[BSPAN + 1];
    __shared__ int lcsr[BSPAN * LSTRIDE];   // 98*97*4 = 38024 B
    int b = blockIdx.x;
    int base = b * BSPAN;
    int span = NN - base;
    if (span <= 0) return;
    if (span > BSPAN) span = BSPAN;
    int tid = threadIdx.x;
    for (int i = tid; i < span; i += 256) lcnt[i] = 0;
    __syncthreads();
    int p0 = bbase[b], p1 = bbase[b + 1];
    for (int i = p0 + tid; i < p1; i += 256) {
        int wd = epack[i];
        int ld = wd >> 17;
        int slot = atomicAdd(&lcnt[ld], 1);
        if (slot < KMAX) lcsr[ld * LSTRIDE + slot] = wd & 0x1FFFF;
    }
    __syncthreads();
    if (tid == 0) {
        int run = 0;
        for (int i = 0; i < span; i++) { lbase[i] = run; run += min(lcnt[i], KMAX); }
        lbase[span] = run;
    }
    __syncthreads();
    for (int i = tid; i < span; i += 256) off[base + i] = p0 + lbase[i];
    if (base + span == NN && tid == 0) off[NN] = p0 + lbase[span];
    int m = lbase[span];
    for (int j = tid; j < m; j += 256) {
        int lo = 0, hi = span - 1;
        while (lo < hi) {
            int mid = (lo + hi + 1) >> 1;
            if (lbase[mid] <= j) lo = mid; else hi = mid - 1;
        }
        srcs[p0 + j] = lcsr[lo * LSTRIDE + (j - lbase[lo])];
    }
}

__device__ __forceinline__ unsigned bf16rn(float f) {
    unsigned b = __float_as_uint(f);
    return (b + 0x7fffu + ((b >> 16) & 1u)) >> 16;   // RNE
}

__device__ __forceinline__ void acc_row(float* a, uint4 v) {
    a[0] += __uint_as_float(v.x << 16);
    a[1] += __uint_as_float(v.x & 0xffff0000u);
    a[2] += __uint_as_float(v.y << 16);
    a[3] += __uint_as_float(v.y & 0xffff0000u);
    a[4] += __uint_as_float(v.z << 16);
    a[5] += __uint_as_float(v.z & 0xffff0000u);
    a[6] += __uint_as_float(v.w << 16);
    a[7] += __uint_as_float(v.w & 0xffff0000u);
}

// ---- projection q(bf16) = BN(h) @ w1, 4-way K-split; q rows = 64B.
template <int FIN>
__global__ __launch_bounds__(256) void proj_kernel(const float* __restrict__ hin,
                                                   const float* __restrict__ w1,
                                                   const float* __restrict__ stats_prev,
                                                   const float* __restrict__ gamma,
                                                   const float* __restrict__ beta,
                                                   uint4* __restrict__ q4) {
    constexpr int JC = FIN / 4;           // K rows per wave: 32 (FIN=128) / 8 (FIN=32)
    __shared__ float sa[32], sc[32];
    __shared__ float part[4 * 64 * 33];   // [wv][node][ch], +1 pad -> 33792 B
    int tid = threadIdx.x;
    if constexpr (FIN == 32) {
        if (tid < 32) {
            float mean = stats_prev[tid] * (1.0f / NN);
            float var  = fmaxf(stats_prev[32 + tid] * (1.0f / NN) - mean * mean, 0.f);
            float av = gamma[tid] * rsqrtf(var + 1e-5f);
            sa[tid] = av;
            sc[tid] = beta[tid] - mean * av;
        }
        __syncthreads();
    }
    int wv = __builtin_amdgcn_readfirstlane(tid >> 6);   // K-part, wave-uniform
    int ln = tid & 63;                                   // node within block
    int n = blockIdx.x * 64 + ln;
    float acc[32];
#pragma unroll
    for (int c = 0; c < 32; c++) acc[c] = 0.f;
    if (n < NN) {
        const float4* h4 = (const float4*)(hin + (size_t)n * FIN + wv * JC);
        float hv[JC];
#pragma unroll
        for (int k = 0; k < JC / 4; k++) {
            float4 v = h4[k];
            hv[4*k] = v.x; hv[4*k+1] = v.y; hv[4*k+2] = v.z; hv[4*k+3] = v.w;
        }
        if constexpr (FIN == 32) {
#pragma unroll
            for (int j = 0; j < JC; j++) hv[j] = fmaf(hv[j], sa[wv * JC + j], sc[wv * JC + j]);
        }
#pragma unroll 4
        for (int j = 0; j < JC; j++) {
            float hvj = hv[j];
            const float* wrow = w1 + (size_t)(wv * JC + j) * 32;  // wave-uniform -> s_load
#pragma unroll
            for (int c = 0; c < 32; c++) acc[c] = fmaf(hvj, wrow[c], acc[c]);
        }
    }
    float* my = part + (wv * 64 + ln) * 33;
#pragma unroll
    for (int c = 0; c < 32; c++) my[c] = acc[c];
    __syncthreads();
    int node = tid >> 2, p = tid & 3;
    int n2 = blockIdx.x * 64 + node;
    if (n2 >= NN) return;
    float r[8];
#pragma unroll
    for (int k = 0; k < 8; k++) {
        int c = p * 8 + k;
        r[k] = (part[(0 * 64 + node) * 33 + c] + part[(1 * 64 + node) * 33 + c])
             + (part[(2 * 64 + node) * 33 + c] + part[(3 * 64 + node) * 33 + c]);
    }
    uint4 u;
    u.x = bf16rn(r[0]) | (bf16rn(r[1]) << 16);
    u.y = bf16rn(r[2]) | (bf16rn(r[3]) << 16);
    u.z = bf16rn(r[4]) | (bf16rn(r[5]) << 16);
    u.w = bf16rn(r[6]) | (bf16rn(r[7]) << 16);
    q4[(size_t)n2 * 4 + p] = u;
}

// ---- fused gather + MLP (r7-verified, DO NOT TOUCH): 4 lanes/node, lane p owns
// channels p*8..p*8+7 (16B slice -> 4-lane coalesced 64B rows), 8-unrolled.
// Epilogue: u -> LDS tile, 32x32 matmul from LDS w2, relu, store h, BN stats.
__global__ __launch_bounds__(256) void gather_mlp_kernel(const uint4* __restrict__ q4,
                                                         const int* __restrict__ srcs,
                                                         const int* __restrict__ off,
                                                         const float* __restrict__ b1,
                                                         const float* __restrict__ w2,
                                                         const float* __restrict__ b2,
                                                         float* __restrict__ hout,
                                                         float* __restrict__ stats) {
    __shared__ float w2t[32 * 33];
    __shared__ float ut[64 * 33];     // 64 nodes x 32 ch (+pad)
    __shared__ float pst[16 * 16];    // 4 waves x 4 p-lanes x (8 s + 8 sq)
    int tid = threadIdx.x;
    for (int i = tid; i < 1024; i += 256) w2t[(i >> 5) * 33 + (i & 31)] = w2[i];
    int t = blockIdx.x * 256 + tid;
    int n = t >> 2;                   // 4 lanes/node, 64 nodes/block
    int p = tid & 3;
    int node64 = tid >> 2;
    bool valid = (n < NN);
    float a[8];
#pragma unroll
    for (int k = 0; k < 8; k++) a[k] = valid ? b1[p * 8 + k] : 0.f;
    if (valid) {
        acc_row(a, q4[(size_t)n * 4 + p]);   // self term
        int o0 = off[n];
        int d = off[n + 1] - o0;
        const int* lst = srcs + o0;
        int i = 0;
        for (; i + 8 <= d; i += 8) {
            int s0 = __builtin_nontemporal_load(lst + i);
            int s1 = __builtin_nontemporal_load(lst + i + 1);
            int s2 = __builtin_nontemporal_load(lst + i + 2);
            int s3 = __builtin_nontemporal_load(lst + i + 3);
            int s4 = __builtin_nontemporal_load(lst + i + 4);
            int s5 = __builtin_nontemporal_load(lst + i + 5);
            int s6 = __builtin_nontemporal_load(lst + i + 6);
            int s7 = __builtin_nontemporal_load(lst + i + 7);
            uint4 v0 = q4[(size_t)s0 * 4 + p];
            uint4 v1 = q4[(size_t)s1 * 4 + p];
            uint4 v2 = q4[(size_t)s2 * 4 + p];
            uint4 v3 = q4[(size_t)s3 * 4 + p];
            uint4 v4 = q4[(size_t)s4 * 4 + p];
            uint4 v5 = q4[(size_t)s5 * 4 + p];
            uint4 v6 = q4[(size_t)s6 * 4 + p];
            uint4 v7 = q4[(size_t)s7 * 4 + p];
            acc_row(a, v0); acc_row(a, v1); acc_row(a, v2); acc_row(a, v3);
            acc_row(a, v4); acc_row(a, v5); acc_row(a, v6); acc_row(a, v7);
        }
        for (; i < d; i++) {
            int s = __builtin_nontemporal_load(lst + i);
            acc_row(a, q4[(size_t)s * 4 + p]);
        }
    }
    // u = relu(z) -> LDS tile
    float* urow = ut + node64 * 33 + p * 8;
#pragma unroll
    for (int k = 0; k < 8; k++) urow[k] = fmaxf(a[k], 0.f);
    __syncthreads();
    // 32x32 matmul: this lane computes channels p*8..p*8+7 of node node64
    int base = p * 8;
    float o[8];
#pragma unroll
    for (int k = 0; k < 8; k++) o[k] = valid ? b2[base + k] : 0.f;
    const float* un = ut + node64 * 33;
#pragma unroll 8
    for (int j = 0; j < 32; j++) {
        float uj = un[j];
        const float* wr = w2t + j * 33 + base;
#pragma unroll
        for (int k = 0; k < 8; k++) o[k] = fmaf(uj, wr[k], o[k]);
    }
#pragma unroll
    for (int k = 0; k < 8; k++) o[k] = fmaxf(o[k], 0.f);
    if (valid) {
        f32x4 h0, h1;
        h0.x = o[0]; h0.y = o[1]; h0.z = o[2]; h0.w = o[3];
        h1.x = o[4]; h1.y = o[5]; h1.z = o[6]; h1.w = o[7];
        f32x4* hr = (f32x4*)(hout + (size_t)n * 32 + base);
        __builtin_nontemporal_store(h0, hr);
        __builtin_nontemporal_store(h1, hr + 1);
    } else {
#pragma unroll
        for (int k = 0; k < 8; k++) o[k] = 0.f;
    }
    // BN stats: reduce across the wave's 16 nodes (same-p lanes stride 4)
    float s[8], q[8];
#pragma unroll
    for (int k = 0; k < 8; k++) { s[k] = o[k]; q[k] = o[k] * o[k]; }
#pragma unroll
    for (int m = 4; m < 64; m <<= 1) {
#pragma unroll
        for (int k = 0; k < 8; k++) {
            s[k] += __shfl_xor(s[k], m);
            q[k] += __shfl_xor(q[k], m);
        }
    }
    int wv = tid >> 6;
    if ((tid & 63) < 4) {
        float* ps = pst + (wv * 4 + p) * 16;
#pragma unroll
        for (int k = 0; k < 8; k++) { ps[k] = s[k]; ps[8 + k] = q[k]; }
    }
    __syncthreads();
    if (tid < 64) {
        int c = tid & 31;
        int issq = tid >> 5;
        int psel = c >> 3, k = c & 7;
        float acc = 0.f;
#pragma unroll
        for (int w = 0; w < 4; w++) acc += pst[(w * 4 + psel) * 16 + issq * 8 + k];
        atomicAdd(&stats[issq * 32 + c], acc);
    }
}

// ---- pooling: segment sums of raw h3 (sorted batch -> run-length flush)
#define PR 16
__global__ __launch_bounds__(256) void pool_kernel(const float* __restrict__ h,
                                                   const int* __restrict__ batch,
                                                   float* __restrict__ pooled,
                                                   float* __restrict__ pcnt) {
    int t = blockIdx.x * 256 + threadIdx.x;
    int c = t & 31;
    int g = t >> 5;
    int r0 = g * PR;
    if (r0 >= NN) return;
    int r1 = min(r0 + PR, NN);
    int cur = batch[r0];
    float acc = 0.f, cn = 0.f;
    for (int rr = r0; rr < r1; rr++) {
        int b = batch[rr];
        if (b != cur) {
            atomicAdd(&pooled[cur * 32 + c], acc);
            if (c == 0) atomicAdd(&pcnt[cur], cn);
            acc = 0.f; cn = 0.f; cur = b;
        }
        acc += h[(size_t)rr * 32 + c];
        cn += 1.f;
    }
    atomicAdd(&pooled[cur * 32 + c], acc);
    if (c == 0) atomicAdd(&pcnt[cur], cn);
}

// ---- head: BN3 (from raw stats3) on pooled means, fc1+relu, fc2, log_softmax
__global__ __launch_bounds__(128) void head_kernel(const float* __restrict__ pooled,
                                                   const float* __restrict__ pcnt,
                                                   const float* __restrict__ stats3,
                                                   const float* __restrict__ g3,
                                                   const float* __restrict__ be3,
                                                   const float* __restrict__ fc1w,
                                                   const float* __restrict__ fc1b,
                                                   const float* __restrict__ fc2w,
                                                   const float* __restrict__ fc2b,
                                                   float* __restrict__ out) {
    __shared__ float sa[32], sc[32];
    int g = threadIdx.x;
    if (g < 32) {
        float mean = stats3[g] * (1.0f / NN);
        float var  = fmaxf(stats3[32 + g] * (1.0f / NN) - mean * mean, 0.f);
        float av = g3[g] * rsqrtf(var + 1e-5f);
        sa[g] = av;
        sc[g] = be3[g] - mean * av;
    }
    __syncthreads();
    if (g >= BB) return;
    float inv = 1.f / fmaxf(pcnt[g], 1.f);
    float xv[32];
#pragma unroll
    for (int c = 0; c < 32; c++) xv[c] = fmaf(sa[c], pooled[g * 32 + c] * inv, sc[c]);
    float u[32];
#pragma unroll 4
    for (int k = 0; k < 32; k++) {
        float s = fc1b[k];
#pragma unroll
        for (int c = 0; c < 32; c++) s = fmaf(xv[c], fc1w[c * 32 + k], s);
        u[k] = fmaxf(s, 0.f);
    }
    float l[8];
#pragma unroll
    for (int o = 0; o < 8; o++) {
        float s = fc2b[o];
#pragma unroll
        for (int k = 0; k < 32; k++) s = fmaf(u[k], fc2w[k * 8 + o], s);
        l[o] = s;
    }
    float m = l[0];
#pragma unroll
    for (int o = 1; o < 8; o++) m = fmaxf(m, l[o]);
    float se = 0.f;
#pragma unroll
    for (int o = 0; o < 8; o++) se += expf(l[o] - m);
    float lse = logf(se) + m;
#pragma unroll
    for (int o = 0; o < 8; o++) out[g * 8 + o] = l[o] - lse;
}

extern "C" void kernel_launch(void* const* d_in, const int* in_sizes, int n_in,
                              void* d_out, int out_size, void* d_ws, size_t ws_size,
                              hipStream_t stream) {
    const float* x    = (const float*)d_in[0];
    const int*   ei   = (const int*)d_in[1];
    const int*   batch= (const int*)d_in[2];
    const float* w1_0 = (const float*)d_in[3];
    const float* b1_0 = (const float*)d_in[4];
    const float* w2_0 = (const float*)d_in[5];
    const float* b2_0 = (const float*)d_in[6];
    const float* g_0  = (const float*)d_in[7];
    const float* be_0 = (const float*)d_in[8];
    const float* w1s  = (const float*)d_in[9];
    const float* b1s  = (const float*)d_in[10];
    const float* w2s  = (const float*)d_in[11];
    const float* b2s  = (const float*)d_in[12];
    const float* gs   = (const float*)d_in[13];
    const float* bes  = (const float*)d_in[14];
    const float* fc1w = (const float*)d_in[15];
    const float* fc1b = (const float*)d_in[16];
    const float* fc2w = (const float*)d_in[17];
    const float* fc2b = (const float*)d_in[18];
    float* out = (float*)d_out;

    char* ws = (char*)d_ws;
    uint4*    q4     = (uint4*)(ws + Q_OFF);        // [N][4] uint4 (64B rows)
    int*      epack  = (int*)(ws + EPACK_OFF);
    float*    h      = (float*)(ws + H_OFF);
    int*      srcs   = (int*)(ws + SRC_OFF);
    int*      off    = (int*)(ws + OFF_OFF);
    int*      hist   = (int*)(ws + HIST_OFF);
    int*      cursor = (int*)(ws + CUR_OFF);
    int*      bbase  = (int*)(ws + BBASE_OFF);
    float*    stats  = (float*)(ws + STATS_OFF);   // 4 slots x 64
    float*    pooled = (float*)(ws + POOLED_OFF);
    float*    pcnt   = (float*)(ws + PCNT_OFF);
    int*      total  = (int*)(ws + TOTAL_OFF);

    (void)hipMemsetAsync(ws + ZERO_OFF, 0, ZERO_BYTES, stream);

    // CSR build chain
    hist_kernel<<<EBLK, 256, 0, stream>>>(ei, hist, total);
    bucket_scan_kernel<<<1, NBKT, 0, stream>>>(total, bbase, cursor);
    scatter_kernel<<<EBLK, SBT, 0, stream>>>(ei, hist, cursor, epack);
    csr_compact_kernel<<<NBKT, 256, 0, stream>>>(epack, bbase, off, srcs);

    const int pblk = (NN + 63) / 64;
    const int gblk = (NN * 4 + 255) / 256;   // 1563

    // layer 0 (F_IN=128, no input BN)
    proj_kernel<128><<<pblk, 256, 0, stream>>>(x, w1_0, nullptr, nullptr, nullptr, q4);
    gather_mlp_kernel<<<gblk, 256, 0, stream>>>(q4, srcs, off, b1_0, w2_0, b2_0, h, stats);

    // layers 1..3, prev BN computed in proj from raw stats slot
    for (int i = 0; i < 3; i++) {
        const float* st_prev = stats + i * 64;
        proj_kernel<32><<<pblk, 256, 0, stream>>>(h, w1s + i * 1024, st_prev,
                                                  gs + i * 32, bes + i * 32, q4);
        gather_mlp_kernel<<<gblk, 256, 0, stream>>>(q4, srcs, off, b1s + i * 32,
                                                    w2s + i * 1024, b2s + i * 32, h,
                                                    stats + (i + 1) * 64);
    }

    int pthreads = ((NN + PR - 1) / PR) * 32;
    pool_kernel<<<(pthreads + 255) / 256, 256, 0, stream>>>(h, batch, pooled, pcnt);
    head_kernel<<<1, 128, 0, stream>>>(pooled, pcnt, stats + 3 * 64, gs + 2 * 32,
                                       bes + 2 * 32, fc1w, fc1b, fc2w, fc2b, out);
}